// Round 2
// baseline (499.731 us; speedup 1.0000x reference)
//
#include <hip/hip_runtime.h>
#include <hip/hip_bf16.h>
#include <stdint.h>
#include <stddef.h>

#define NB    64      // batch
#define NTOK  784
#define DIMC  256
#define NN2   4
#define NM    8
#define NHW   196
#define NWIN  32      // windows per batch
#define NROWS 2048    // NB*NWIN
#define NK    392
#define NKP   448     // K padded
#define NBIG  38416   // HW*HW source cols
#define NIP   200     // i-stride in ST / Wgbt-permuted rows per j
#define STROW 39200   // 196*200 elements per window-row of ST
#define NPT   39296   // 307*128 padded rows of Wgbt
#define NTT   307

typedef __attribute__((ext_vector_type(4))) float f32x4;
typedef __attribute__((ext_vector_type(8))) short bf16x8;

static __device__ __forceinline__ float bf2f(unsigned short u) {
  union { unsigned int i; float f; } v; v.i = ((unsigned int)u) << 16; return v.f;
}
static __device__ __forceinline__ unsigned short f2bf(float f) {
  union { float f; unsigned int i; } v; v.f = f;
  unsigned int r = v.i + 0x7fffu + ((v.i >> 16) & 1u);  // RNE
  return (unsigned short)(r >> 16);
}

// ---------- kernel 1: compress (x@Wc+bc) + rearrange -> A bf16 [NROWS][NKP]
__global__ __launch_bounds__(256) void k_compress(
    const float* __restrict__ x, const float* __restrict__ Wc,
    const float* __restrict__ bc, unsigned short* __restrict__ Abf) {
  __shared__ float wcs[16 * 256];
  __shared__ float bcs[16];
  const int tid = threadIdx.x;
  const int b  = blockIdx.x / NN2;
  const int n2 = blockIdx.x % NN2;
  for (int idx = tid; idx < 4096; idx += 256) {
    int c = idx >> 4, md = idx & 15;
    wcs[md * 256 + c] = Wc[idx];
  }
  if (tid < 16) bcs[tid] = bc[tid];
  __syncthreads();
  if (tid < NHW) {
    const int h = tid / 7, wcol = tid % 7;
    const int t = h * 28 + n2 * 7 + wcol;
    const float* xp = x + ((size_t)b * NTOK + t) * DIMC;
    float acc[16];
    #pragma unroll
    for (int md = 0; md < 16; ++md) acc[md] = bcs[md];
    for (int c = 0; c < 256; c += 4) {
      const f32x4 xv = *(const f32x4*)(xp + c);
      #pragma unroll
      for (int md = 0; md < 16; ++md) {
        const f32x4 wv = *(const f32x4*)(wcs + md * 256 + c);
        acc[md] += xv[0]*wv[0] + xv[1]*wv[1] + xv[2]*wv[2] + xv[3]*wv[3];
      }
    }
    #pragma unroll
    for (int md = 0; md < 16; ++md) {
      const int m = md >> 1, d = md & 1;
      const int r = b * NWIN + n2 * NM + m;
      Abf[(size_t)r * NKP + tid * 2 + d] = f2bf(acc[md]);
    }
  }
  for (int e = tid; e < NM * (NKP - NK); e += 256) {
    const int m = e / (NKP - NK);
    const int k = NK + (e % (NKP - NK));
    const int r = b * NWIN + n2 * NM + m;
    Abf[(size_t)r * NKP + k] = 0;
  }
}

// ---------- kernel 2: Wg [NK][NBIG] f32 -> Wgbt [NPT][NKP] bf16, rows PERMUTED:
//            source col n = i*196+j  ->  dest row n' = j*200+i
__global__ __launch_bounds__(256) void k_wgt(
    const float* __restrict__ Wg, unsigned short* __restrict__ Wgbt) {
  __shared__ float tile[64][65];
  const int bid = blockIdx.x;
  const int n0 = (bid % 601) * 64;
  const int k0 = (bid / 601) * 64;
  const int tid = threadIdx.x;
  for (int idx = tid; idx < 4096; idx += 256) {
    const int kk = idx >> 6, nn = idx & 63;
    const int k = k0 + kk, n = n0 + nn;
    tile[nn][kk] = (k < NK && n < NBIG) ? Wg[(size_t)k * NBIG + n] : 0.f;
  }
  __syncthreads();
  for (int idx = tid; idx < 4096; idx += 256) {
    const int nn = idx >> 6, kk = idx & 63;
    const int n = n0 + nn;
    if (n < NBIG) {
      const int i = n / NHW, j = n % NHW;
      Wgbt[(size_t)(j * NIP + i) * NKP + (k0 + kk)] = f2bf(tile[nn][kk]);
    }
  }
}

// ---------- kernel 2b: zero the never-written Wgbt rows (i in [196,200), and n' >= 39200)
__global__ __launch_bounds__(256) void k_zero(unsigned short* __restrict__ Wgbt) {
  const int bid = blockIdx.x;
  int nprime;
  if (bid < 784) { const int j = bid >> 2, i = 196 + (bid & 3); nprime = j * NIP + i; }
  else           { nprime = STROW + (bid - 784); }
  unsigned int* p = (unsigned int*)(Wgbt + (size_t)nprime * NKP);
  if (threadIdx.x < 224) p[threadIdx.x] = 0u;
}

// ---------- kernel 3: ST[rc][STROW] bf16 = A @ Wgbt^T + bg (MFMA, mt-inner + XCD swizzle)
__global__ __launch_bounds__(256) void k_gemm(
    const unsigned short* __restrict__ A,
    const unsigned short* __restrict__ Bt,
    const float* __restrict__ bg,
    unsigned short* __restrict__ S) {
  __shared__ __align__(128) short As[128 * 64];
  __shared__ __align__(128) short Bs[128 * 64];
  const int tid = threadIdx.x;
  const int w = tid >> 6, lane = tid & 63;
  // bijective XCD-chunked swizzle, then mt-inner decomposition
  const int nwg = gridDim.x;
  const int q = nwg >> 3, rr = nwg & 7;
  const int xcd = blockIdx.x & 7, pos = blockIdx.x >> 3;
  const int wg = (xcd < rr ? xcd * (q + 1) : rr * (q + 1) + (xcd - rr) * q) + pos;
  const int mtiles = nwg / NTT;
  const int nt = wg / mtiles, mt = wg % mtiles;
  const int m0 = mt * 128, n0 = nt * 128;
  const int wm = (w >> 1) * 64, wn = (w & 1) * 64;
  const int lrow = lane >> 3, lcol = (lane & 7) * 8;
  f32x4 acc[4][4] = {};
  for (int kt = 0; kt < NKP; kt += 64) {
    #pragma unroll
    for (int is = 0; is < 4; ++is) {
      const int gg = w * 4 + is;
      const int row = gg * 8 + lrow;
      const unsigned short* ga = A  + (size_t)(m0 + row) * NKP + kt + lcol;
      const unsigned short* gb = Bt + (size_t)(n0 + row) * NKP + kt + lcol;
      __builtin_amdgcn_global_load_lds(
          (const __attribute__((address_space(1))) void*)ga,
          (__attribute__((address_space(3))) void*)((char*)As + gg * 1024), 16, 0, 0);
      __builtin_amdgcn_global_load_lds(
          (const __attribute__((address_space(1))) void*)gb,
          (__attribute__((address_space(3))) void*)((char*)Bs + gg * 1024), 16, 0, 0);
    }
    __syncthreads();
    #pragma unroll
    for (int kk = 0; kk < 2; ++kk) {
      bf16x8 af[4], bfr[4];
      #pragma unroll
      for (int i = 0; i < 4; ++i) {
        af[i]  = *(const bf16x8*)(As + (wm + i * 16 + (lane & 15)) * 64 + kk * 32 + (lane >> 4) * 8);
        bfr[i] = *(const bf16x8*)(Bs + (wn + i * 16 + (lane & 15)) * 64 + kk * 32 + (lane >> 4) * 8);
      }
      #pragma unroll
      for (int mi = 0; mi < 4; ++mi)
        #pragma unroll
        for (int ni = 0; ni < 4; ++ni)
          acc[mi][ni] = __builtin_amdgcn_mfma_f32_16x16x32_bf16(af[mi], bfr[ni], acc[mi][ni], 0, 0, 0);
    }
    __syncthreads();
  }
  #pragma unroll
  for (int ni = 0; ni < 4; ++ni) {
    const int col = n0 + wn + ni * 16 + (lane & 15);
    if (col < STROW) {
      const int i = col % NIP, j = col / NIP;
      const float bgv = (i < NHW) ? bg[i * NHW + j] : 0.f;
      #pragma unroll
      for (int mi = 0; mi < 4; ++mi)
        #pragma unroll
        for (int e = 0; e < 4; ++e) {
          const int row = m0 + wm + mi * 16 + (lane >> 4) * 4 + e;
          S[(size_t)row * STROW + col] = f2bf(acc[mi][ni][e] + bgv);
        }
    }
  }
}

// ---------- kernel 4: per-window row-softmax (from global, in registers) + MFMA mix
// PT stride 232 elements (464 B = 29*16: 16B-aligned b128 frag reads)
#define PTS 232
__global__ __launch_bounds__(256) void k_softmax_mix(
    const unsigned short* __restrict__ ST, const float* __restrict__ x,
    float* __restrict__ out, int row0) {
  __shared__ unsigned short PT[208 * PTS];   // [j][i] normalized weights bf16
  __shared__ unsigned short xvT[32 * PTS];   // [c][i] bf16
  const int tid = threadIdx.x, w = tid >> 6, lane = tid & 63;
  const int r = row0 + blockIdx.x;
  const int b = r >> 5, win = r & 31, n2 = win >> 3, m = win & 7;

  // phase 1: xvT[c][i] = x[b, t(i), m*32+c]
  for (int idx = tid; idx < 1568; idx += 256) {
    const int i = idx >> 3, c4 = (idx & 7) * 4;
    const int t = (i / 7) * 28 + n2 * 7 + (i % 7);
    const f32x4 v = *(const f32x4*)(x + ((size_t)b * NTOK + t) * DIMC + m * 32 + c4);
    xvT[(c4 + 0) * PTS + i] = f2bf(v[0]);
    xvT[(c4 + 1) * PTS + i] = f2bf(v[1]);
    xvT[(c4 + 2) * PTS + i] = f2bf(v[2]);
    xvT[(c4 + 3) * PTS + i] = f2bf(v[3]);
  }
  for (int idx = tid; idx < 2048; idx += 256) {   // zero pads i in [196,232)
    const int c = idx >> 6, i = 196 + (idx & 63);
    if (i < PTS) xvT[c * PTS + i] = 0;
  }

  // phase 2: softmax rows; wave w handles j = 4*jj + w
  const unsigned short* Sb = ST + (size_t)blockIdx.x * STROW;
  const int i0 = lane * 4;
  auto process = [&](int j, uint2 rawv) {
    float v[4];
    v[0] = (i0 + 0 < NHW && lane < 50) ? bf2f((unsigned short)(rawv.x & 0xffffu)) : -3.0e38f;
    v[1] = (i0 + 1 < NHW && lane < 50) ? bf2f((unsigned short)(rawv.x >> 16))     : -3.0e38f;
    v[2] = (i0 + 2 < NHW && lane < 50) ? bf2f((unsigned short)(rawv.y & 0xffffu)) : -3.0e38f;
    v[3] = (i0 + 3 < NHW && lane < 50) ? bf2f((unsigned short)(rawv.y >> 16))     : -3.0e38f;
    float mx = fmaxf(fmaxf(v[0], v[1]), fmaxf(v[2], v[3]));
    #pragma unroll
    for (int off = 32; off >= 1; off >>= 1) mx = fmaxf(mx, __shfl_xor(mx, off));
    float e[4], s = 0.f;
    #pragma unroll
    for (int qq = 0; qq < 4; ++qq) {
      e[qq] = (v[qq] > -1.0e38f) ? __expf(v[qq] - mx) : 0.f;
      s += e[qq];
    }
    #pragma unroll
    for (int off = 32; off >= 1; off >>= 1) s += __shfl_xor(s, off);
    const float inv = 1.f / s;
    if (lane < 50) {
      uint2 o;
      o.x = (unsigned)f2bf(e[0] * inv) | ((unsigned)f2bf(e[1] * inv) << 16);
      o.y = (unsigned)f2bf(e[2] * inv) | ((unsigned)f2bf(e[3] * inv) << 16);
      *(uint2*)&PT[j * PTS + i0] = o;
    } else if (lane < 58) {          // zero pads i in [200,232)
      uint2 z; z.x = 0u; z.y = 0u;
      *(uint2*)&PT[j * PTS + i0] = z;
    }
  };
  for (int jb = 0; jb < 48; jb += 8) {
    uint2 raw[8];
    #pragma unroll
    for (int u = 0; u < 8; ++u) {
      raw[u].x = 0u; raw[u].y = 0u;
      if (lane < 50)
        raw[u] = *(const uint2*)(Sb + (size_t)((jb + u) * 4 + w) * NIP + i0);
    }
    #pragma unroll
    for (int u = 0; u < 8; ++u) process((jb + u) * 4 + w, raw[u]);
  }
  {
    uint2 t0; t0.x = 0u; t0.y = 0u;
    if (lane < 50) t0 = *(const uint2*)(Sb + (size_t)(192 + w) * NIP + i0);
    process(192 + w, t0);
  }
  __syncthreads();

  // phase 3: MFMA  outT[j][c] = sum_i PT[j][i] * xvT[c][i]
  bf16x8 bfr[2][7];
  #pragma unroll
  for (int ct = 0; ct < 2; ++ct)
    #pragma unroll
    for (int kk = 0; kk < 7; ++kk)
      bfr[ct][kk] = *(const bf16x8*)&xvT[(ct * 16 + (lane & 15)) * PTS + kk * 32 + (lane >> 4) * 8];
  for (int jt = w; jt < 13; jt += 4) {
    f32x4 acc0 = {0.f, 0.f, 0.f, 0.f}, acc1 = {0.f, 0.f, 0.f, 0.f};
    #pragma unroll
    for (int kk = 0; kk < 7; ++kk) {
      const bf16x8 af = *(const bf16x8*)&PT[(jt * 16 + (lane & 15)) * PTS + kk * 32 + (lane >> 4) * 8];
      acc0 = __builtin_amdgcn_mfma_f32_16x16x32_bf16(af, bfr[0][kk], acc0, 0, 0, 0);
      acc1 = __builtin_amdgcn_mfma_f32_16x16x32_bf16(af, bfr[1][kk], acc1, 0, 0, 0);
    }
    const int c = lane & 15;
    #pragma unroll
    for (int e = 0; e < 4; ++e) {
      const int j = jt * 16 + (lane >> 4) * 4 + e;
      if (j < NHW) {
        const int t2 = (j / 7) * 28 + n2 * 7 + (j % 7);
        float* op = out + ((size_t)b * NTOK + t2) * DIMC + m * 32;
        op[c] = acc0[e];
        op[c + 16] = acc1[e];
      }
    }
  }
}

extern "C" void kernel_launch(void* const* d_in, const int* in_sizes, int n_in,
                              void* d_out, int out_size, void* d_ws, size_t ws_size,
                              hipStream_t stream) {
  const float* x  = (const float*)d_in[0];
  const float* Wc = (const float*)d_in[1];
  const float* bc = (const float*)d_in[2];
  const float* Wg = (const float*)d_in[3];
  const float* bg = (const float*)d_in[4];
  float* out = (float*)d_out;

  char* ws = (char*)d_ws;
  const size_t wgbt_bytes = (size_t)NPT * NKP * 2;     // 35.2 MB
  const size_t a_bytes    = (size_t)NROWS * NKP * 2;   // 1.8 MB
  unsigned short* Wgbt = (unsigned short*)ws;
  unsigned short* Abf  = (unsigned short*)(ws + wgbt_bytes);
  unsigned short* ST   = (unsigned short*)(ws + wgbt_bytes + a_bytes);
  const size_t srow_bytes = (size_t)STROW * 2;         // 78.4 KB per window-row

  size_t avail = (ws_size > wgbt_bytes + a_bytes) ? (ws_size - wgbt_bytes - a_bytes) : 0;
  int rows_chunk = (int)(avail / srow_bytes);
  rows_chunk = (rows_chunk / 128) * 128;
  if (rows_chunk > NROWS) rows_chunk = NROWS;
  if (rows_chunk < 128)  rows_chunk = 128;

  hipLaunchKernelGGL(k_compress, dim3(NB * NN2), dim3(256), 0, stream, x, Wc, bc, Abf);
  hipLaunchKernelGGL(k_wgt, dim3(601 * 7), dim3(256), 0, stream, Wg, Wgbt);
  hipLaunchKernelGGL(k_zero, dim3(784 + (NPT - STROW)), dim3(256), 0, stream, Wgbt);
  for (int row0 = 0; row0 < NROWS; row0 += rows_chunk) {
    int rc = NROWS - row0; if (rc > rows_chunk) rc = rows_chunk;
    hipLaunchKernelGGL(k_gemm, dim3((rc / 128) * NTT), dim3(256), 0, stream,
                       Abf + (size_t)row0 * NKP, Wgbt, bg, ST);
    hipLaunchKernelGGL(k_softmax_mix, dim3(rc), dim3(256), 0, stream, ST, x, out, row0);
  }
}

// Round 3
// 265.632 us; speedup vs baseline: 1.8813x; 1.8813x over previous
//
#include <hip/hip_runtime.h>
#include <hip/hip_bf16.h>
#include <stdint.h>
#include <stddef.h>

#define NB    64      // batch
#define NTOK  784
#define DIMC  256
#define NN2   4
#define NM    8
#define NHW   196
#define NWIN  32      // windows per batch
#define NROWS 2048    // NB*NWIN
#define NK    392
#define NKP   448     // K padded
#define NBIG  38416   // HW*HW source cols
#define NIP   200     // i-stride within a j-row of E
#define STROW 39200   // 196*200 used elements per window-row of E
#define STROW2 39232  // padded window-row stride (16B-mult, covers frag over-read)
#define NPT   39296   // 307*128 padded rows of Wgbt
#define NTT   307
#define PTS   232     // xvT i-stride (2-way-free LDS banking)

typedef __attribute__((ext_vector_type(4))) float f32x4;
typedef __attribute__((ext_vector_type(8))) short bf16x8;

static __device__ __forceinline__ float bf2f(unsigned short u) {
  union { unsigned int i; float f; } v; v.i = ((unsigned int)u) << 16; return v.f;
}
static __device__ __forceinline__ unsigned short f2bf(float f) {
  union { float f; unsigned int i; } v; v.f = f;
  unsigned int r = v.i + 0x7fffu + ((v.i >> 16) & 1u);  // RNE
  return (unsigned short)(r >> 16);
}

// ---------- kernel 1: compress (x@Wc+bc) + rearrange -> A bf16 [NROWS][NKP]
__global__ __launch_bounds__(256) void k_compress(
    const float* __restrict__ x, const float* __restrict__ Wc,
    const float* __restrict__ bc, unsigned short* __restrict__ Abf) {
  __shared__ float wcs[16 * 256];
  __shared__ float bcs[16];
  const int tid = threadIdx.x;
  const int b  = blockIdx.x / NN2;
  const int n2 = blockIdx.x % NN2;
  for (int idx = tid; idx < 4096; idx += 256) {
    int c = idx >> 4, md = idx & 15;
    wcs[md * 256 + c] = Wc[idx];
  }
  if (tid < 16) bcs[tid] = bc[tid];
  __syncthreads();
  if (tid < NHW) {
    const int h = tid / 7, wcol = tid % 7;
    const int t = h * 28 + n2 * 7 + wcol;
    const float* xp = x + ((size_t)b * NTOK + t) * DIMC;
    float acc[16];
    #pragma unroll
    for (int md = 0; md < 16; ++md) acc[md] = bcs[md];
    for (int c = 0; c < 256; c += 4) {
      const f32x4 xv = *(const f32x4*)(xp + c);
      #pragma unroll
      for (int md = 0; md < 16; ++md) {
        const f32x4 wv = *(const f32x4*)(wcs + md * 256 + c);
        acc[md] += xv[0]*wv[0] + xv[1]*wv[1] + xv[2]*wv[2] + xv[3]*wv[3];
      }
    }
    #pragma unroll
    for (int md = 0; md < 16; ++md) {
      const int m = md >> 1, d = md & 1;
      const int r = b * NWIN + n2 * NM + m;
      Abf[(size_t)r * NKP + tid * 2 + d] = f2bf(acc[md]);
    }
  }
  for (int e = tid; e < NM * (NKP - NK); e += 256) {
    const int m = e / (NKP - NK);
    const int k = NK + (e % (NKP - NK));
    const int r = b * NWIN + n2 * NM + m;
    Abf[(size_t)r * NKP + k] = 0;
  }
}

// ---------- kernel 2: Wg [NK][NBIG] f32 -> Wgbt [NPT][NKP] bf16, rows permuted:
//            source col n = i*196+j  ->  dest row n' = j*200+i
__global__ __launch_bounds__(256) void k_wgt(
    const float* __restrict__ Wg, unsigned short* __restrict__ Wgbt) {
  __shared__ float tile[64][65];
  const int bid = blockIdx.x;
  const int n0 = (bid % 601) * 64;
  const int k0 = (bid / 601) * 64;
  const int tid = threadIdx.x;
  for (int idx = tid; idx < 4096; idx += 256) {
    const int kk = idx >> 6, nn = idx & 63;
    const int k = k0 + kk, n = n0 + nn;
    tile[nn][kk] = (k < NK && n < NBIG) ? Wg[(size_t)k * NBIG + n] : 0.f;
  }
  __syncthreads();
  for (int idx = tid; idx < 4096; idx += 256) {
    const int nn = idx >> 6, kk = idx & 63;
    const int n = n0 + nn;
    if (n < NBIG) {
      const int i = n / NHW, j = n % NHW;
      Wgbt[(size_t)(j * NIP + i) * NKP + (k0 + kk)] = f2bf(tile[nn][kk]);
    }
  }
}

// ---------- kernel 2b: zero Wgbt pad rows n' = j*200+i, i in [196,200)
// (unwritten poison there would turn into NaN logits -> NaN E read by k_mix)
__global__ __launch_bounds__(256) void k_zero(unsigned short* __restrict__ Wgbt) {
  const int j = blockIdx.x >> 2, i = 196 + (blockIdx.x & 3);
  unsigned int* p = (unsigned int*)(Wgbt + (size_t)(j * NIP + i) * NKP);
  if (threadIdx.x < 224) p[threadIdx.x] = 0u;
}

// ---------- kernel 3: E[rc][STROW2] bf16 = exp(A @ Wgbt^T + bg)  (MFMA, XCD swizzle)
__global__ __launch_bounds__(256) void k_gemm(
    const unsigned short* __restrict__ A,
    const unsigned short* __restrict__ Bt,
    const float* __restrict__ bg,
    unsigned short* __restrict__ S) {
  __shared__ __align__(128) short As[128 * 64];
  __shared__ __align__(128) short Bs[128 * 64];
  const int tid = threadIdx.x;
  const int w = tid >> 6, lane = tid & 63;
  const int nwg = gridDim.x;
  const int q = nwg >> 3, rr = nwg & 7;
  const int xcd = blockIdx.x & 7, pos = blockIdx.x >> 3;
  const int wg = (xcd < rr ? xcd * (q + 1) : rr * (q + 1) + (xcd - rr) * q) + pos;
  const int mtiles = nwg / NTT;
  const int nt = wg / mtiles, mt = wg % mtiles;
  const int m0 = mt * 128, n0 = nt * 128;
  const int wm = (w >> 1) * 64, wn = (w & 1) * 64;
  const int lrow = lane >> 3, lcol = (lane & 7) * 8;
  f32x4 acc[4][4] = {};
  for (int kt = 0; kt < NKP; kt += 64) {
    #pragma unroll
    for (int is = 0; is < 4; ++is) {
      const int gg = w * 4 + is;
      const int row = gg * 8 + lrow;
      const unsigned short* ga = A  + (size_t)(m0 + row) * NKP + kt + lcol;
      const unsigned short* gb = Bt + (size_t)(n0 + row) * NKP + kt + lcol;
      __builtin_amdgcn_global_load_lds(
          (const __attribute__((address_space(1))) void*)ga,
          (__attribute__((address_space(3))) void*)((char*)As + gg * 1024), 16, 0, 0);
      __builtin_amdgcn_global_load_lds(
          (const __attribute__((address_space(1))) void*)gb,
          (__attribute__((address_space(3))) void*)((char*)Bs + gg * 1024), 16, 0, 0);
    }
    __syncthreads();
    #pragma unroll
    for (int kk = 0; kk < 2; ++kk) {
      bf16x8 af[4], bfr[4];
      #pragma unroll
      for (int i = 0; i < 4; ++i) {
        af[i]  = *(const bf16x8*)(As + (wm + i * 16 + (lane & 15)) * 64 + kk * 32 + (lane >> 4) * 8);
        bfr[i] = *(const bf16x8*)(Bs + (wn + i * 16 + (lane & 15)) * 64 + kk * 32 + (lane >> 4) * 8);
      }
      #pragma unroll
      for (int mi = 0; mi < 4; ++mi)
        #pragma unroll
        for (int ni = 0; ni < 4; ++ni)
          acc[mi][ni] = __builtin_amdgcn_mfma_f32_16x16x32_bf16(af[mi], bfr[ni], acc[mi][ni], 0, 0, 0);
    }
    __syncthreads();
  }
  #pragma unroll
  for (int ni = 0; ni < 4; ++ni) {
    const int col = n0 + wn + ni * 16 + (lane & 15);
    if (col < STROW) {
      const int i = col % NIP, j = col / NIP;
      const float bgv = (i < NHW) ? bg[i * NHW + j] : 0.f;
      #pragma unroll
      for (int mi = 0; mi < 4; ++mi)
        #pragma unroll
        for (int e = 0; e < 4; ++e) {
          const int row = m0 + wm + mi * 16 + (lane >> 4) * 4 + e;
          S[(size_t)row * STROW2 + col] = f2bf(__expf(acc[mi][ni][e] + bgv));
        }
    } else if (col < STROW2) {
      #pragma unroll
      for (int mi = 0; mi < 4; ++mi)
        #pragma unroll
        for (int e = 0; e < 4; ++e) {
          const int row = m0 + wm + mi * 16 + (lane >> 4) * 4 + e;
          S[(size_t)row * STROW2 + col] = 0;
        }
    }
  }
}

// ---------- kernel 4: mix. outT[j][c] = (sum_i E[j][i]*xvT[c][i]) / (sum_i E[j][i])
// A-frags straight from global E; denominator via computed ones-fragment (D col 0).
__global__ __launch_bounds__(256) void k_mix(
    const unsigned short* __restrict__ E, const float* __restrict__ x,
    float* __restrict__ out, int row0) {
  __shared__ unsigned short xvT[32 * PTS];   // [c][i] bf16
  const int tid = threadIdx.x, w = tid >> 6, lane = tid & 63;
  const int r = row0 + blockIdx.x;
  const int b = r >> 5, win = r & 31, n2 = win >> 3, m = win & 7;

  // phase 1: xvT[c][i] = x[b, t(i), m*32+c]; zero pads i in [196,232)
  for (int idx = tid; idx < 1568; idx += 256) {
    const int i = idx >> 3, c4 = (idx & 7) * 4;
    const int t = (i / 7) * 28 + n2 * 7 + (i % 7);
    const f32x4 v = *(const f32x4*)(x + ((size_t)b * NTOK + t) * DIMC + m * 32 + c4);
    xvT[(c4 + 0) * PTS + i] = f2bf(v[0]);
    xvT[(c4 + 1) * PTS + i] = f2bf(v[1]);
    xvT[(c4 + 2) * PTS + i] = f2bf(v[2]);
    xvT[(c4 + 3) * PTS + i] = f2bf(v[3]);
  }
  for (int idx = tid; idx < 32 * (PTS - NHW); idx += 256) {
    const int c = idx / (PTS - NHW), i = NHW + idx % (PTS - NHW);
    xvT[c * PTS + i] = 0;
  }
  __syncthreads();

  // hoist B-frags (channels) and build ones-frags for the denominator
  bf16x8 bfr[2][7];
  #pragma unroll
  for (int ct = 0; ct < 2; ++ct)
    #pragma unroll
    for (int kk = 0; kk < 7; ++kk)
      bfr[ct][kk] = *(const bf16x8*)&xvT[(ct * 16 + (lane & 15)) * PTS + kk * 32 + (lane >> 4) * 8];
  const bool den = (lane & 15) == 0;
  bf16x8 oneA, oneB;   // oneA: kk 0..5 (i<192); oneB: kk==6 (i in [192,224))
  #pragma unroll
  for (int e = 0; e < 8; ++e) {
    oneA[e] = den ? (short)0x3F80 : (short)0;
    const int i6 = 192 + (lane >> 4) * 8 + e;
    oneB[e] = (den && i6 < NHW) ? (short)0x3F80 : (short)0;
  }

  const unsigned short* Eb = E + (size_t)blockIdx.x * STROW2;
  for (int jt = w; jt < 13; jt += 4) {
    const int jA = jt * 16 + (lane & 15);
    const unsigned short* rp = Eb + (size_t)(jA < NHW ? jA : NHW - 1) * NIP + (lane >> 4) * 8;
    f32x4 a0 = {0.f,0.f,0.f,0.f}, a1 = {0.f,0.f,0.f,0.f}, ad = {0.f,0.f,0.f,0.f};
    #pragma unroll
    for (int kk = 0; kk < 7; ++kk) {
      const bf16x8 af = *(const bf16x8*)(rp + kk * 32);
      a0 = __builtin_amdgcn_mfma_f32_16x16x32_bf16(af, bfr[0][kk], a0, 0, 0, 0);
      a1 = __builtin_amdgcn_mfma_f32_16x16x32_bf16(af, bfr[1][kk], a1, 0, 0, 0);
      ad = __builtin_amdgcn_mfma_f32_16x16x32_bf16(af, (kk < 6) ? oneA : oneB, ad, 0, 0, 0);
    }
    const int c = lane & 15;
    #pragma unroll
    for (int e = 0; e < 4; ++e) {
      const int j = jt * 16 + (lane >> 4) * 4 + e;
      const float dv = __shfl(ad[e], lane & 48);   // broadcast D col 0 (denominator)
      if (j < NHW) {
        const float inv = 1.f / dv;
        const int t2 = (j / 7) * 28 + n2 * 7 + (j % 7);
        float* op = out + ((size_t)b * NTOK + t2) * DIMC + m * 32;
        op[c] = a0[e] * inv;
        op[c + 16] = a1[e] * inv;
      }
    }
  }
}

extern "C" void kernel_launch(void* const* d_in, const int* in_sizes, int n_in,
                              void* d_out, int out_size, void* d_ws, size_t ws_size,
                              hipStream_t stream) {
  const float* x  = (const float*)d_in[0];
  const float* Wc = (const float*)d_in[1];
  const float* bc = (const float*)d_in[2];
  const float* Wg = (const float*)d_in[3];
  const float* bg = (const float*)d_in[4];
  float* out = (float*)d_out;

  char* ws = (char*)d_ws;
  const size_t wgbt_bytes = (size_t)NPT * NKP * 2;     // 35.2 MB
  const size_t a_bytes    = (size_t)NROWS * NKP * 2;   // 1.8 MB
  unsigned short* Wgbt = (unsigned short*)ws;
  unsigned short* Abf  = (unsigned short*)(ws + wgbt_bytes);
  unsigned short* ST   = (unsigned short*)(ws + wgbt_bytes + a_bytes);
  const size_t srow_bytes = (size_t)STROW2 * 2;        // 78.5 KB per window-row

  size_t avail = (ws_size > wgbt_bytes + a_bytes) ? (ws_size - wgbt_bytes - a_bytes) : 0;
  int rows_chunk = (int)(avail / srow_bytes);
  rows_chunk = (rows_chunk / 128) * 128;
  if (rows_chunk > NROWS) rows_chunk = NROWS;
  if (rows_chunk < 128)  rows_chunk = 128;

  hipLaunchKernelGGL(k_compress, dim3(NB * NN2), dim3(256), 0, stream, x, Wc, bc, Abf);
  hipLaunchKernelGGL(k_wgt, dim3(601 * 7), dim3(256), 0, stream, Wg, Wgbt);
  hipLaunchKernelGGL(k_zero, dim3(784), dim3(256), 0, stream, Wgbt);
  for (int row0 = 0; row0 < NROWS; row0 += rows_chunk) {
    int rc = NROWS - row0; if (rc > rows_chunk) rc = rows_chunk;
    hipLaunchKernelGGL(k_gemm, dim3((rc / 128) * NTT), dim3(256), 0, stream,
                       Abf + (size_t)row0 * NKP, Wgbt, bg, ST);
    hipLaunchKernelGGL(k_mix, dim3(rc), dim3(256), 0, stream, ST, x, out, row0);
  }
}

// Round 4
// 256.468 us; speedup vs baseline: 1.9485x; 1.0357x over previous
//
#include <hip/hip_runtime.h>
#include <hip/hip_bf16.h>
#include <stdint.h>
#include <stddef.h>

#define NB    64      // batch
#define NTOK  784
#define DIMC  256
#define NN2   4
#define NM    8
#define NHW   196
#define NWIN  32      // windows per batch
#define NROWS 2048    // NB*NWIN
#define NK    392
#define NKP   448     // K padded
#define NBIG  38416   // HW*HW source cols
#define NIP   200     // i-stride within a j-row of E
#define STROW 39200   // 196*200 used elements per window-row of E
#define STROW2 39232  // padded window-row stride
#define NPT   39296   // 307*128 padded rows of Wgbt
#define NTT   307
#define PTS   232     // xvT i-stride

typedef __attribute__((ext_vector_type(4))) float f32x4;
typedef __attribute__((ext_vector_type(8))) short bf16x8;

static __device__ __forceinline__ float bf2f(unsigned short u) {
  union { unsigned int i; float f; } v; v.i = ((unsigned int)u) << 16; return v.f;
}
static __device__ __forceinline__ unsigned short f2bf(float f) {
  union { float f; unsigned int i; } v; v.f = f;
  unsigned int r = v.i + 0x7fffu + ((v.i >> 16) & 1u);  // RNE
  return (unsigned short)(r >> 16);
}

// ---------- kernel 1: compress (x@Wc+bc) + rearrange -> A bf16 [NROWS][NKP]
__global__ __launch_bounds__(256) void k_compress(
    const float* __restrict__ x, const float* __restrict__ Wc,
    const float* __restrict__ bc, unsigned short* __restrict__ Abf) {
  __shared__ float wcs[16 * 256];
  __shared__ float bcs[16];
  const int tid = threadIdx.x;
  const int b  = blockIdx.x / NN2;
  const int n2 = blockIdx.x % NN2;
  for (int idx = tid; idx < 4096; idx += 256) {
    int c = idx >> 4, md = idx & 15;
    wcs[md * 256 + c] = Wc[idx];
  }
  if (tid < 16) bcs[tid] = bc[tid];
  __syncthreads();
  if (tid < NHW) {
    const int h = tid / 7, wcol = tid % 7;
    const int t = h * 28 + n2 * 7 + wcol;
    const float* xp = x + ((size_t)b * NTOK + t) * DIMC;
    float acc[16];
    #pragma unroll
    for (int md = 0; md < 16; ++md) acc[md] = bcs[md];
    for (int c = 0; c < 256; c += 4) {
      const f32x4 xv = *(const f32x4*)(xp + c);
      #pragma unroll
      for (int md = 0; md < 16; ++md) {
        const f32x4 wv = *(const f32x4*)(wcs + md * 256 + c);
        acc[md] += xv[0]*wv[0] + xv[1]*wv[1] + xv[2]*wv[2] + xv[3]*wv[3];
      }
    }
    #pragma unroll
    for (int md = 0; md < 16; ++md) {
      const int m = md >> 1, d = md & 1;
      const int r = b * NWIN + n2 * NM + m;
      Abf[(size_t)r * NKP + tid * 2 + d] = f2bf(acc[md]);
    }
  }
  for (int e = tid; e < NM * (NKP - NK); e += 256) {
    const int m = e / (NKP - NK);
    const int k = NK + (e % (NKP - NK));
    const int r = b * NWIN + n2 * NM + m;
    Abf[(size_t)r * NKP + k] = 0;
  }
}

// ---------- kernel 2: Wg [NK][NBIG] f32 -> Wgbt [NPT][NKP] bf16, rows permuted:
//            source col n = i*196+j  ->  dest row n' = j*200+i
__global__ __launch_bounds__(256) void k_wgt(
    const float* __restrict__ Wg, unsigned short* __restrict__ Wgbt) {
  __shared__ float tile[64][65];
  const int bid = blockIdx.x;
  const int n0 = (bid % 601) * 64;
  const int k0 = (bid / 601) * 64;
  const int tid = threadIdx.x;
  for (int idx = tid; idx < 4096; idx += 256) {
    const int kk = idx >> 6, nn = idx & 63;
    const int k = k0 + kk, n = n0 + nn;
    tile[nn][kk] = (k < NK && n < NBIG) ? Wg[(size_t)k * NBIG + n] : 0.f;
  }
  __syncthreads();
  for (int idx = tid; idx < 4096; idx += 256) {
    const int nn = idx >> 6, kk = idx & 63;
    const int n = n0 + nn;
    if (n < NBIG) {
      const int i = n / NHW, j = n % NHW;
      Wgbt[(size_t)(j * NIP + i) * NKP + (k0 + kk)] = f2bf(tile[nn][kk]);
    }
  }
}

// ---------- kernel 2b: zero Wgbt pad rows n' = j*200+i, i in [196,200)
__global__ __launch_bounds__(256) void k_zero(unsigned short* __restrict__ Wgbt) {
  const int j = blockIdx.x >> 2, i = 196 + (blockIdx.x & 3);
  unsigned int* p = (unsigned int*)(Wgbt + (size_t)(j * NIP + i) * NKP);
  if (threadIdx.x < 224) p[threadIdx.x] = 0u;
}

// ---------- kernel 3: E[rc][STROW2] bf16 = exp(A @ Wgbt^T + bg)
// T2 XOR-swizzled LDS (pre-swizzled global source, linear global_load_lds dest,
// swizzled ds_read) + double-buffered issue-early staging, 1 barrier per K-step.
__global__ __launch_bounds__(256) void k_gemm(
    const unsigned short* __restrict__ A,
    const unsigned short* __restrict__ Bt,
    const float* __restrict__ bg,
    unsigned short* __restrict__ S) {
  __shared__ __align__(128) short As[2][128 * 64];
  __shared__ __align__(128) short Bs[2][128 * 64];
  const int tid = threadIdx.x;
  const int w = tid >> 6, lane = tid & 63;
  const int nwg = gridDim.x;
  const int q = nwg >> 3, rr = nwg & 7;
  const int xcd = blockIdx.x & 7, pos = blockIdx.x >> 3;
  const int wg = (xcd < rr ? xcd * (q + 1) : rr * (q + 1) + (xcd - rr) * q) + pos;
  const int mtiles = nwg / NTT;
  const int nt = wg / mtiles, mt = wg % mtiles;
  const int m0 = mt * 128, n0 = nt * 128;
  const int wm = (w >> 1) * 64, wn = (w & 1) * 64;
  const int lrow = lane >> 3;
  // source column pre-swizzled so LDS[row][slot s] = global granule s ^ (row&7)
  const int lcolsw = ((lane & 7) ^ lrow) * 8;

  const unsigned short* Arow = A  + (size_t)(m0 + w * 32 + lrow) * NKP + lcolsw;
  const unsigned short* Brow = Bt + (size_t)(n0 + w * 32 + lrow) * NKP + lcolsw;

  auto stage = [&](int kt, int buf) {
    #pragma unroll
    for (int is = 0; is < 4; ++is) {
      const int gg = w * 4 + is;
      __builtin_amdgcn_global_load_lds(
          (const __attribute__((address_space(1))) void*)(Arow + (size_t)is * 8 * NKP + kt),
          (__attribute__((address_space(3))) void*)((char*)As[buf] + gg * 1024), 16, 0, 0);
      __builtin_amdgcn_global_load_lds(
          (const __attribute__((address_space(1))) void*)(Brow + (size_t)is * 8 * NKP + kt),
          (__attribute__((address_space(3))) void*)((char*)Bs[buf] + gg * 1024), 16, 0, 0);
    }
  };

  f32x4 acc[4][4] = {};
  stage(0, 0);
  __syncthreads();
  const int lq = lane >> 4;        // quarter-group
  const int lx = (lane & 7);       // row&7 of the frag rows this lane reads
  for (int t = 0; t < 7; ++t) {
    const int buf = t & 1;
    if (t < 6) stage((t + 1) * 64, buf ^ 1);
    const short* ab = As[buf];
    const short* bb = Bs[buf];
    #pragma unroll
    for (int kk = 0; kk < 2; ++kk) {
      bf16x8 af[4], bfr[4];
      #pragma unroll
      for (int i = 0; i < 4; ++i) {
        const int row = wm + i * 16 + (lane & 15);
        const int slot = ((kk * 4 + lq) ^ lx) * 8;
        af[i]  = *(const bf16x8*)(ab + row * 64 + slot);
        const int rowb = wn + i * 16 + (lane & 15);
        bfr[i] = *(const bf16x8*)(bb + rowb * 64 + slot);
      }
      #pragma unroll
      for (int mi = 0; mi < 4; ++mi)
        #pragma unroll
        for (int ni = 0; ni < 4; ++ni)
          acc[mi][ni] = __builtin_amdgcn_mfma_f32_16x16x32_bf16(af[mi], bfr[ni], acc[mi][ni], 0, 0, 0);
    }
    __syncthreads();
  }

  #pragma unroll
  for (int ni = 0; ni < 4; ++ni) {
    const int col = n0 + wn + ni * 16 + (lane & 15);
    if (col < STROW) {
      const int i = col % NIP, j = col / NIP;
      const float bgv = (i < NHW) ? bg[i * NHW + j] : 0.f;
      #pragma unroll
      for (int mi = 0; mi < 4; ++mi)
        #pragma unroll
        for (int e = 0; e < 4; ++e) {
          const int row = m0 + wm + mi * 16 + (lane >> 4) * 4 + e;
          S[(size_t)row * STROW2 + col] = f2bf(__expf(acc[mi][ni][e] + bgv));
        }
    } else if (col < STROW2) {
      #pragma unroll
      for (int mi = 0; mi < 4; ++mi)
        #pragma unroll
        for (int e = 0; e < 4; ++e) {
          const int row = m0 + wm + mi * 16 + (lane >> 4) * 4 + e;
          S[(size_t)row * STROW2 + col] = 0;
        }
    }
  }
}

// ---------- kernel 4: mix. outT[j][c] = (sum_i E[j][i]*xvT[c][i]) / (sum_i E[j][i])
__global__ __launch_bounds__(256) void k_mix(
    const unsigned short* __restrict__ E, const float* __restrict__ x,
    float* __restrict__ out, int row0) {
  __shared__ unsigned short xvT[32 * PTS];   // [c][i] bf16
  const int tid = threadIdx.x, w = tid >> 6, lane = tid & 63;
  const int r = row0 + blockIdx.x;
  const int b = r >> 5, win = r & 31, n2 = win >> 3, m = win & 7;

  for (int idx = tid; idx < 1568; idx += 256) {
    const int i = idx >> 3, c4 = (idx & 7) * 4;
    const int t = (i / 7) * 28 + n2 * 7 + (i % 7);
    const f32x4 v = *(const f32x4*)(x + ((size_t)b * NTOK + t) * DIMC + m * 32 + c4);
    xvT[(c4 + 0) * PTS + i] = f2bf(v[0]);
    xvT[(c4 + 1) * PTS + i] = f2bf(v[1]);
    xvT[(c4 + 2) * PTS + i] = f2bf(v[2]);
    xvT[(c4 + 3) * PTS + i] = f2bf(v[3]);
  }
  for (int idx = tid; idx < 32 * (PTS - NHW); idx += 256) {
    const int c = idx / (PTS - NHW), i = NHW + idx % (PTS - NHW);
    xvT[c * PTS + i] = 0;
  }
  __syncthreads();

  bf16x8 bfr[2][7];
  #pragma unroll
  for (int ct = 0; ct < 2; ++ct)
    #pragma unroll
    for (int kk = 0; kk < 7; ++kk)
      bfr[ct][kk] = *(const bf16x8*)&xvT[(ct * 16 + (lane & 15)) * PTS + kk * 32 + (lane >> 4) * 8];
  const bool den = (lane & 15) == 0;
  bf16x8 oneA, oneB;
  #pragma unroll
  for (int e = 0; e < 8; ++e) {
    oneA[e] = den ? (short)0x3F80 : (short)0;
    const int i6 = 192 + (lane >> 4) * 8 + e;
    oneB[e] = (den && i6 < NHW) ? (short)0x3F80 : (short)0;
  }

  const unsigned short* Eb = E + (size_t)blockIdx.x * STROW2;
  for (int jt = w; jt < 13; jt += 4) {
    const int jA = jt * 16 + (lane & 15);
    const unsigned short* rp = Eb + (size_t)(jA < NHW ? jA : NHW - 1) * NIP + (lane >> 4) * 8;
    f32x4 a0 = {0.f,0.f,0.f,0.f}, a1 = {0.f,0.f,0.f,0.f}, ad = {0.f,0.f,0.f,0.f};
    #pragma unroll
    for (int kk = 0; kk < 7; ++kk) {
      const bf16x8 af = *(const bf16x8*)(rp + kk * 32);
      a0 = __builtin_amdgcn_mfma_f32_16x16x32_bf16(af, bfr[0][kk], a0, 0, 0, 0);
      a1 = __builtin_amdgcn_mfma_f32_16x16x32_bf16(af, bfr[1][kk], a1, 0, 0, 0);
      ad = __builtin_amdgcn_mfma_f32_16x16x32_bf16(af, (kk < 6) ? oneA : oneB, ad, 0, 0, 0);
    }
    const int c = lane & 15;
    #pragma unroll
    for (int e = 0; e < 4; ++e) {
      const int j = jt * 16 + (lane >> 4) * 4 + e;
      const float dv = __shfl(ad[e], lane & 48);
      if (j < NHW) {
        const float inv = 1.f / dv;
        const int t2 = (j / 7) * 28 + n2 * 7 + (j % 7);
        float* op = out + ((size_t)b * NTOK + t2) * DIMC + m * 32;
        op[c] = a0[e] * inv;
        op[c + 16] = a1[e] * inv;
      }
    }
  }
}

extern "C" void kernel_launch(void* const* d_in, const int* in_sizes, int n_in,
                              void* d_out, int out_size, void* d_ws, size_t ws_size,
                              hipStream_t stream) {
  const float* x  = (const float*)d_in[0];
  const float* Wc = (const float*)d_in[1];
  const float* bc = (const float*)d_in[2];
  const float* Wg = (const float*)d_in[3];
  const float* bg = (const float*)d_in[4];
  float* out = (float*)d_out;

  char* ws = (char*)d_ws;
  const size_t wgbt_bytes = (size_t)NPT * NKP * 2;     // 35.2 MB
  const size_t a_bytes    = (size_t)NROWS * NKP * 2;   // 1.8 MB
  unsigned short* Wgbt = (unsigned short*)ws;
  unsigned short* Abf  = (unsigned short*)(ws + wgbt_bytes);
  unsigned short* ST   = (unsigned short*)(ws + wgbt_bytes + a_bytes);
  const size_t srow_bytes = (size_t)STROW2 * 2;

  size_t avail = (ws_size > wgbt_bytes + a_bytes) ? (ws_size - wgbt_bytes - a_bytes) : 0;
  int rows_chunk = (int)(avail / srow_bytes);
  rows_chunk = (rows_chunk / 128) * 128;
  if (rows_chunk > NROWS) rows_chunk = NROWS;
  if (rows_chunk < 128)  rows_chunk = 128;

  hipLaunchKernelGGL(k_compress, dim3(NB * NN2), dim3(256), 0, stream, x, Wc, bc, Abf);
  hipLaunchKernelGGL(k_wgt, dim3(601 * 7), dim3(256), 0, stream, Wg, Wgbt);
  hipLaunchKernelGGL(k_zero, dim3(784), dim3(256), 0, stream, Wgbt);
  for (int row0 = 0; row0 < NROWS; row0 += rows_chunk) {
    int rc = NROWS - row0; if (rc > rows_chunk) rc = rows_chunk;
    hipLaunchKernelGGL(k_gemm, dim3((rc / 128) * NTT), dim3(256), 0, stream,
                       Abf + (size_t)row0 * NKP, Wgbt, bg, ST);
    hipLaunchKernelGGL(k_mix, dim3(rc), dim3(256), 0, stream, ST, x, out, row0);
  }
}